// Round 1
// baseline (2692.142 us; speedup 1.0000x reference)
//
#include <hip/hip_runtime.h>

#define NHW 2304
#define NB  8
#define NS  20
#define NC  512

struct f4 { float v[4]; };

// out[b,o,n] = bias[o] + sum_k w[o,k] * x[b][k][n]
// x layout: batch stride xbs, row stride NHW. out: batch stride obs, row stride NHW.
__global__ __launch_bounds__(256)
void gemm_wx(const float* __restrict__ x, long xbs,
             const float* __restrict__ w, int K,
             const float* __restrict__ bias,
             float* __restrict__ out, long obs)
{
    __shared__ __align__(16) float wsT[16][68];  // [k][o], padded
    __shared__ __align__(16) float xsT[16][64];  // [k][n]
    const int tid  = threadIdx.x;
    const int nBase = blockIdx.x * 64;
    const int oBase = blockIdx.y * 64;
    const int b     = blockIdx.z;
    const float* xb = x + (long)b * xbs;
    const int tx = tid & 15, ty = tid >> 4;
    const int w_oo = tid >> 2;
    const int w_kq = (tid & 3) * 4;
    const int x_nn = (tid & 15) * 4;
    const int x_kk = tid >> 4;
    float acc[4][4] = {};
    for (int k0 = 0; k0 < K; k0 += 16) {
        f4 wv = *reinterpret_cast<const f4*>(&w[(long)(oBase + w_oo) * K + k0 + w_kq]);
        f4 xv = *reinterpret_cast<const f4*>(&xb[(long)(k0 + x_kk) * NHW + nBase + x_nn]);
        __syncthreads();
        #pragma unroll
        for (int e = 0; e < 4; ++e) wsT[w_kq + e][w_oo] = wv.v[e];
        *reinterpret_cast<f4*>(&xsT[x_kk][x_nn]) = xv;
        __syncthreads();
        #pragma unroll
        for (int kk = 0; kk < 16; ++kk) {
            f4 a  = *reinterpret_cast<const f4*>(&wsT[kk][ty * 4]);
            f4 xx = *reinterpret_cast<const f4*>(&xsT[kk][tx * 4]);
            #pragma unroll
            for (int i = 0; i < 4; ++i)
                #pragma unroll
                for (int j = 0; j < 4; ++j)
                    acc[i][j] += a.v[i] * xx.v[j];
        }
    }
    float* ob = out + (long)b * obs;
    #pragma unroll
    for (int i = 0; i < 4; ++i) {
        int o = oBase + ty * 4 + i;
        float bb = bias[o];
        f4 r;
        #pragma unroll
        for (int j = 0; j < 4; ++j) r.v[j] = acc[i][j] + bb;
        *reinterpret_cast<f4*>(&ob[(long)o * NHW + nBase + tx * 4]) = r;
    }
}

// out[n][m] = scale * sum_k A[k][n] * Bm[k][m]   (A,B k-major with row stride NHW)
__global__ __launch_bounds__(256)
void gemm_tn(const float* __restrict__ A, const float* __restrict__ Bm,
             float* __restrict__ out, int K, float scale)
{
    __shared__ __align__(16) float asT[16][64];
    __shared__ __align__(16) float bsT[16][64];
    const int tid = threadIdx.x;
    const int mBase = blockIdx.x * 64;
    const int nBase = blockIdx.y * 64;
    const int tx = tid & 15, ty = tid >> 4;
    const int l_nn = (tid & 15) * 4, l_kk = tid >> 4;
    float acc[4][4] = {};
    for (int k0 = 0; k0 < K; k0 += 16) {
        f4 av = *reinterpret_cast<const f4*>(&A[(long)(k0 + l_kk) * NHW + nBase + l_nn]);
        f4 bv = *reinterpret_cast<const f4*>(&Bm[(long)(k0 + l_kk) * NHW + mBase + l_nn]);
        __syncthreads();
        *reinterpret_cast<f4*>(&asT[l_kk][l_nn]) = av;
        *reinterpret_cast<f4*>(&bsT[l_kk][l_nn]) = bv;
        __syncthreads();
        #pragma unroll
        for (int kk = 0; kk < 16; ++kk) {
            f4 a  = *reinterpret_cast<const f4*>(&asT[kk][ty * 4]);
            f4 bb = *reinterpret_cast<const f4*>(&bsT[kk][tx * 4]);
            #pragma unroll
            for (int i = 0; i < 4; ++i)
                #pragma unroll
                for (int j = 0; j < 4; ++j)
                    acc[i][j] += a.v[i] * bb.v[j];
        }
    }
    #pragma unroll
    for (int i = 0; i < 4; ++i) {
        f4 r;
        #pragma unroll
        for (int j = 0; j < 4; ++j) r.v[j] = acc[i][j] * scale;
        *reinterpret_cast<f4*>(&out[(long)(nBase + ty * 4 + i) * NHW + mBase + tx * 4]) = r;
    }
}

// out[c][n] = sum_m A[c][m] * Bt[n][m]   (A: C x NHW row-major, Bt: NHW x NHW row-major)
__global__ __launch_bounds__(256)
void gemm_nt(const float* __restrict__ A, const float* __restrict__ Bt,
             float* __restrict__ out)
{
    __shared__ __align__(16) float asT[16][68];
    __shared__ __align__(16) float bsT[16][68];
    const int tid = threadIdx.x;
    const int nBase = blockIdx.x * 64;
    const int cBase = blockIdx.y * 64;
    const int tx = tid & 15, ty = tid >> 4;
    const int l_row = tid >> 2;
    const int l_mq  = (tid & 3) * 4;
    float acc[4][4] = {};
    for (int m0 = 0; m0 < NHW; m0 += 16) {
        f4 av = *reinterpret_cast<const f4*>(&A[(long)(cBase + l_row) * NHW + m0 + l_mq]);
        f4 bv = *reinterpret_cast<const f4*>(&Bt[(long)(nBase + l_row) * NHW + m0 + l_mq]);
        __syncthreads();
        #pragma unroll
        for (int e = 0; e < 4; ++e) asT[l_mq + e][l_row] = av.v[e];
        #pragma unroll
        for (int e = 0; e < 4; ++e) bsT[l_mq + e][l_row] = bv.v[e];
        __syncthreads();
        #pragma unroll
        for (int kk = 0; kk < 16; ++kk) {
            f4 a  = *reinterpret_cast<const f4*>(&asT[kk][ty * 4]);
            f4 bb = *reinterpret_cast<const f4*>(&bsT[kk][tx * 4]);
            #pragma unroll
            for (int i = 0; i < 4; ++i)
                #pragma unroll
                for (int j = 0; j < 4; ++j)
                    acc[i][j] += a.v[i] * bb.v[j];
        }
    }
    #pragma unroll
    for (int i = 0; i < 4; ++i) {
        f4 r;
        #pragma unroll
        for (int j = 0; j < 4; ++j) r.v[j] = acc[i][j];
        *reinterpret_cast<f4*>(&out[(long)(cBase + ty * 4 + i) * NHW + nBase + tx * 4]) = r;
    }
}

// row softmax over NHW=2304 (9 x 256)
__global__ __launch_bounds__(256)
void softmax_rows(float* __restrict__ p)
{
    float* pr = p + (long)blockIdx.x * NHW;
    const int tid = threadIdx.x;
    float v[9];
    float mx = -1e30f;
    #pragma unroll
    for (int i = 0; i < 9; ++i) { v[i] = pr[tid + i * 256]; mx = fmaxf(mx, v[i]); }
    __shared__ float red_mx[4];
    #pragma unroll
    for (int off = 32; off > 0; off >>= 1) mx = fmaxf(mx, __shfl_down(mx, off, 64));
    if ((tid & 63) == 0) red_mx[tid >> 6] = mx;
    __syncthreads();
    mx = fmaxf(fmaxf(red_mx[0], red_mx[1]), fmaxf(red_mx[2], red_mx[3]));
    float sum = 0.f;
    #pragma unroll
    for (int i = 0; i < 9; ++i) { v[i] = expf(v[i] - mx); sum += v[i]; }
    __shared__ float red_sm[4];
    #pragma unroll
    for (int off = 32; off > 0; off >>= 1) sum += __shfl_down(sum, off, 64);
    if ((tid & 63) == 0) red_sm[tid >> 6] = sum;
    __syncthreads();
    sum = (red_sm[0] + red_sm[1]) + (red_sm[2] + red_sm[3]);
    const float inv = 1.f / sum;
    #pragma unroll
    for (int i = 0; i < 9; ++i) pr[tid + i * 256] = v[i] * inv;
}

// word attention: logits over s, softmax(axis=s), mask, renorm -> attnw[b,s,n]
__global__ __launch_bounds__(256)
void word_attn(const float* __restrict__ vis, const float* __restrict__ query,
               const int* __restrict__ word_id, float* __restrict__ attnw)
{
    __shared__ float qsh[NS][NC];   // 40 KB
    __shared__ float msk[NS];
    const int b = blockIdx.y;
    const int tid = threadIdx.x;
    for (int idx = tid; idx < NS * NC; idx += 256)
        qsh[idx / NC][idx % NC] = query[(long)b * NS * NC + idx];
    if (tid < NS) msk[tid] = (word_id[b * NS + tid] != 0) ? 1.f : 0.f;
    __syncthreads();
    const int n = blockIdx.x * 256 + tid;
    const float* vb = vis + (long)b * NC * NHW + n;
    float acc[NS] = {};
    for (int c = 0; c < NC; ++c) {
        float vv = vb[(long)c * NHW];
        #pragma unroll
        for (int s = 0; s < NS; ++s) acc[s] += qsh[s][c] * vv;
    }
    float mx = acc[0];
    #pragma unroll
    for (int s = 1; s < NS; ++s) mx = fmaxf(mx, acc[s]);
    float sum = 0.f;
    #pragma unroll
    for (int s = 0; s < NS; ++s) { acc[s] = expf(acc[s] - mx); sum += acc[s]; }
    const float inv = 1.f / sum;
    float msum = 0.f;
    #pragma unroll
    for (int s = 0; s < NS; ++s) { acc[s] *= inv * msk[s]; msum += acc[s]; }
    const float r = 1.f / msum;
    #pragma unroll
    for (int s = 0; s < NS; ++s)
        attnw[((long)b * NS + s) * NHW + n] = acc[s] * r;
}

// wemb[b,c,n] = sum_s query[b,s,c] * attnw[b,s,n], written into cat[b, 512+c, n]
__global__ __launch_bounds__(256)
void word_emb(const float* __restrict__ attnw, const float* __restrict__ query,
              float* __restrict__ cat)
{
    __shared__ float qsh[NS][NC];
    const int b = blockIdx.y;
    const int tid = threadIdx.x;
    for (int idx = tid; idx < NS * NC; idx += 256)
        qsh[idx / NC][idx % NC] = query[(long)b * NS * NC + idx];
    __syncthreads();
    const int n = blockIdx.x * 256 + tid;
    float a[NS];
    #pragma unroll
    for (int s = 0; s < NS; ++s) a[s] = attnw[((long)b * NS + s) * NHW + n];
    float* ob = cat + ((long)b * 1024 + 512) * NHW + n;
    for (int c = 0; c < NC; ++c) {
        float acc = 0.f;
        #pragma unroll
        for (int s = 0; s < NS; ++s) acc += qsh[s][c] * a[s];
        ob[(long)c * NHW] = acc;
    }
}

// wcomb[o,c] = w1[o,c] + (c<512 ? w2[o,c] : 0);  bcomb[o] = w1_b[o] + w2_b[o]
__global__ __launch_bounds__(256)
void make_wcomb(const float* __restrict__ w1, const float* __restrict__ w1b,
                const float* __restrict__ w2, const float* __restrict__ w2b,
                float* __restrict__ wcomb, float* __restrict__ bcomb)
{
    const int o = blockIdx.x;
    const int tid = threadIdx.x;
    for (int c = tid; c < 1024; c += 256)
        wcomb[o * 1024 + c] = w1[o * 1024 + c] + (c < 512 ? w2[o * 512 + c] : 0.f);
    if (tid == 0) bcomb[o] = w1b[o] + w2b[o];
}

extern "C" void kernel_launch(void* const* d_in, const int* in_sizes, int n_in,
                              void* d_out, int out_size, void* d_ws, size_t ws_size,
                              hipStream_t stream)
{
    const float* key   = (const float*)d_in[0];
    const float* query = (const float*)d_in[1];
    const int*   wid   = (const int*)d_in[2];
    const float* wv_w  = (const float*)d_in[3];
    const float* wv_b  = (const float*)d_in[4];
    const float* fk_w  = (const float*)d_in[5];
    const float* fk_b  = (const float*)d_in[6];
    const float* fq_w  = (const float*)d_in[7];
    const float* fq_b  = (const float*)d_in[8];
    const float* fv_w  = (const float*)d_in[9];
    const float* fv_b  = (const float*)d_in[10];
    const float* w1_w  = (const float*)d_in[11];
    const float* w1_b  = (const float*)d_in[12];
    const float* w2_w  = (const float*)d_in[13];
    const float* w2_b  = (const float*)d_in[14];
    float* out = (float*)d_out;

    float* cat   = (float*)d_ws;                      // 8*1024*2304  (ctx | wemb)
    float* vis   = cat   + (size_t)8 * 1024 * NHW;    // 8*512*2304
    float* vbuf  = vis   + (size_t)8 * 512 * NHW;     // 8*512*2304
    float* attnw = vbuf  + (size_t)8 * 512 * NHW;     // 8*20*2304
    float* pbuf  = attnw + (size_t)8 * NS * NHW;      // 2304*2304 (per-batch reuse)
    float* wcomb = pbuf  + (size_t)NHW * NHW;         // 512*1024
    float* bcomb = wcomb + (size_t)512 * 1024;        // 512
    float* kbuf  = vis;                               // reuse vis after word_attn
    float* qbuf  = vis + (size_t)8 * 256 * NHW;

    dim3 blk(256);

    // 1. vis = wv @ key + wv_b
    gemm_wx<<<dim3(36, 8, 8), blk, 0, stream>>>(key, (long)512 * NHW, wv_w, 512, wv_b,
                                                vis, (long)512 * NHW);
    // 2. word attention weights (softmax over s, mask, renorm)
    word_attn<<<dim3(9, 8), blk, 0, stream>>>(vis, query, wid, attnw);
    // 3. wemb -> cat[:, 512:1024, :]
    word_emb<<<dim3(9, 8), blk, 0, stream>>>(attnw, query, cat);
    // 4. k = fk @ key + fk_b   (overwrites vis region; vis already consumed)
    gemm_wx<<<dim3(36, 4, 8), blk, 0, stream>>>(key, (long)512 * NHW, fk_w, 512, fk_b,
                                                kbuf, (long)256 * NHW);
    // 5. q = fq @ wemb + fq_b
    gemm_wx<<<dim3(36, 4, 8), blk, 0, stream>>>(cat + (size_t)512 * NHW, (long)1024 * NHW,
                                                fq_w, 512, fq_b, qbuf, (long)256 * NHW);
    // 6. v = fv @ key + fv_b
    gemm_wx<<<dim3(36, 8, 8), blk, 0, stream>>>(key, (long)512 * NHW, fv_w, 512, fv_b,
                                                vbuf, (long)512 * NHW);
    // 7. combined epilogue weight
    make_wcomb<<<dim3(512), blk, 0, stream>>>(w1_w, w1_b, w2_w, w2_b, wcomb, bcomb);
    // 8. non-local attention, per batch (pbuf reused serially)
    for (int b = 0; b < NB; ++b) {
        const float* qb = qbuf + (size_t)b * 256 * NHW;
        const float* kb = kbuf + (size_t)b * 256 * NHW;
        const float* vb = vbuf + (size_t)b * 512 * NHW;
        gemm_tn<<<dim3(36, 36), blk, 0, stream>>>(qb, kb, pbuf, 256, 0.0625f);
        softmax_rows<<<dim3(NHW), blk, 0, stream>>>(pbuf);
        gemm_nt<<<dim3(36, 8), blk, 0, stream>>>(vb, pbuf, cat + (size_t)b * 1024 * NHW);
    }
    // 9. out2 = wcomb @ cat + bcomb
    gemm_wx<<<dim3(36, 8, 8), blk, 0, stream>>>(cat, (long)1024 * NHW, wcomb, 1024, bcomb,
                                                out, (long)512 * NHW);
}

// Round 3
// 450.699 us; speedup vs baseline: 5.9733x; 5.9733x over previous
//
#include <hip/hip_runtime.h>

#define NHW 2304
#define NB  8
#define NS  20
#define NC  512

typedef unsigned short u16;
typedef short short8 __attribute__((ext_vector_type(8)));
typedef unsigned short u16x8 __attribute__((ext_vector_type(8)));
typedef float f32x4 __attribute__((ext_vector_type(4)));

__device__ __forceinline__ float b2f(u16 u) {
    unsigned int v = ((unsigned int)u) << 16;
    return __builtin_bit_cast(float, v);
}
__device__ __forceinline__ u16 f2b(float f) {
    unsigned int u = __builtin_bit_cast(unsigned int, f);
    u += 0x7fffu + ((u >> 16) & 1u);
    return (u16)(u >> 16);
}

__device__ __forceinline__ void load_lds16(const void* g, void* l) {
    __builtin_amdgcn_global_load_lds((const __attribute__((address_space(1))) void*)g,
                                     (__attribute__((address_space(3))) void*)l, 16, 0, 0);
}

// ---------------------------------------------------------------------------
// Uniform bf16 NT GEMM: C[b](MxN) = scale * A[b](MxK,lda) * B[b](NxK,ldb)^T (+bias)
// M,N multiples of 128; K multiple of 32. 256 thr, 4 waves 2x2, 128x128 tile.
// bias_mode: 0 none, 1 per-row, 2 per-col. out_f32: 1 fp32 else bf16.
// ---------------------------------------------------------------------------
__global__ __launch_bounds__(256)
void gemm_nt_bf16(const u16* __restrict__ A, long As, int lda,
                  const u16* __restrict__ B, long Bs, int ldb,
                  void* __restrict__ C, long Cs, int ldc,
                  int K, const float* __restrict__ bias, int bias_mode,
                  float scale, int out_f32)
{
    __shared__ __align__(16) u16 sA[128 * 32];
    __shared__ __align__(16) u16 sB[128 * 32];
    const int tid   = threadIdx.x;
    const int b     = blockIdx.z;
    const int nBase = blockIdx.x * 128;
    const int mBase = blockIdx.y * 128;
    const u16* Ab = A + (size_t)b * As + (size_t)mBase * lda;
    const u16* Bb = B + (size_t)b * Bs + (size_t)nBase * ldb;
    const int lane = tid & 63;
    const int wave = tid >> 6;
    const int wr = wave >> 1, wc = wave & 1;
    const int str = tid >> 2;
    const int stk = (tid & 3) * 8;
    f32x4 acc[4][4] = {};
    for (int k0 = 0; k0 < K; k0 += 32) {
        __syncthreads();
        load_lds16(&Ab[(size_t)str * lda + k0 + stk],        &sA[tid * 8]);
        load_lds16(&Ab[(size_t)(str + 64) * lda + k0 + stk], &sA[2048 + tid * 8]);
        load_lds16(&Bb[(size_t)str * ldb + k0 + stk],        &sB[tid * 8]);
        load_lds16(&Bb[(size_t)(str + 64) * ldb + k0 + stk], &sB[2048 + tid * 8]);
        __syncthreads();
        short8 af[4], bg[4];
        #pragma unroll
        for (int i = 0; i < 4; ++i)
            af[i] = *(const short8*)&sA[(wr * 64 + i * 16 + (lane & 15)) * 32 + (lane >> 4) * 8];
        #pragma unroll
        for (int j = 0; j < 4; ++j)
            bg[j] = *(const short8*)&sB[(wc * 64 + j * 16 + (lane & 15)) * 32 + (lane >> 4) * 8];
        #pragma unroll
        for (int i = 0; i < 4; ++i)
            #pragma unroll
            for (int j = 0; j < 4; ++j)
                acc[i][j] = __builtin_amdgcn_mfma_f32_16x16x32_bf16(af[i], bg[j], acc[i][j], 0, 0, 0);
    }
    const int r0 = mBase + wr * 64 + (lane >> 4) * 4;
    const int c0 = nBase + wc * 64 + (lane & 15);
    #pragma unroll
    for (int i = 0; i < 4; ++i) {
        #pragma unroll
        for (int r = 0; r < 4; ++r) {
            const int row = r0 + i * 16 + r;
            const float br = (bias_mode == 1) ? bias[row] : 0.f;
            #pragma unroll
            for (int j = 0; j < 4; ++j) {
                const int col = c0 + j * 16;
                float v = acc[i][j][r] * scale;
                v += (bias_mode == 2) ? bias[col] : br;
                if (out_f32)
                    ((float*)C)[(size_t)b * Cs + (size_t)row * ldc + col] = v;
                else
                    ((u16*)C)[(size_t)b * Cs + (size_t)row * ldc + col] = f2b(v);
            }
        }
    }
}

// key (B,512,2304) fp32 -> keyT (B,2304,512) bf16, 64x64 tiles via LDS
__global__ __launch_bounds__(256)
void transpose_key(const float* __restrict__ key, u16* __restrict__ keyT)
{
    __shared__ u16 t[64][72];
    const int b = blockIdx.z;
    const int nBase = blockIdx.x * 64;
    const int cBase = blockIdx.y * 64;
    const int tid = threadIdx.x;
    const float* kb = key + ((size_t)b * NC + cBase) * NHW + nBase;
    const int ln = tid & 63;
    const int lc = tid >> 6;
    #pragma unroll
    for (int r = 0; r < 16; ++r) {
        int c = lc + r * 4;
        t[c][ln] = f2b(kb[(size_t)c * NHW + ln]);
    }
    __syncthreads();
    u16* ob = keyT + ((size_t)b * NHW + nBase) * NC + cBase;
    #pragma unroll
    for (int r = 0; r < 2; ++r) {
        int slot = r * 256 + tid;
        int n = slot >> 3;
        int c0 = (slot & 7) * 8;
        u16x8 v;
        #pragma unroll
        for (int e = 0; e < 8; ++e) v[e] = t[c0 + e][n];
        *(u16x8*)&ob[(size_t)n * NC + c0] = v;
    }
}

__global__ __launch_bounds__(256)
void conv_weights(const float* __restrict__ fk, const float* __restrict__ fq,
                  const float* __restrict__ fv,
                  u16* __restrict__ fkb, u16* __restrict__ fqb, u16* __restrict__ fvb)
{
    int idx = blockIdx.x * 256 + threadIdx.x;   // 524288 total
    if (idx < 131072) fkb[idx] = f2b(fk[idx]);
    else if (idx < 262144) fqb[idx - 131072] = f2b(fq[idx - 131072]);
    else fvb[idx - 262144] = f2b(fv[idx - 262144]);
}

__global__ __launch_bounds__(256)
void make_wcomb(const float* __restrict__ w1, const float* __restrict__ w1b,
                const float* __restrict__ w2, const float* __restrict__ w2b,
                u16* __restrict__ wcb, float* __restrict__ bcomb)
{
    const int o = blockIdx.x;
    const int t = threadIdx.x;
    for (int c = t; c < 1024; c += 256)
        wcb[o * 1024 + c] = f2b(w1[o * 1024 + c] + (c < 512 ? w2[o * 512 + c] : 0.f));
    if (t == 0) bcomb[o] = w1b[o] + w2b[o];
}

// qw[b,s,c] = sum_o query[b,s,o] * wv_w[o,c];  qb[b,s] = sum_o query[b,s,o]*wv_b[o]
__global__ __launch_bounds__(256)
void fold_query_wv(const float* __restrict__ query, const float* __restrict__ wv_w,
                   const float* __restrict__ wv_b,
                   float* __restrict__ qw, float* __restrict__ qb)
{
    __shared__ float qs[NC];
    const int b = blockIdx.y, s = blockIdx.x;
    const int tid = threadIdx.x;
    qs[tid] = query[((size_t)b * NS + s) * NC + tid];
    qs[tid + 256] = query[((size_t)b * NS + s) * NC + tid + 256];
    __syncthreads();
    float a0 = 0.f, a1 = 0.f;
    for (int o = 0; o < NC; ++o) {
        float qv = qs[o];
        a0 += qv * wv_w[(size_t)o * NC + tid];
        a1 += qv * wv_w[(size_t)o * NC + tid + 256];
    }
    qw[((size_t)b * NS + s) * NC + tid] = a0;
    qw[((size_t)b * NS + s) * NC + tid + 256] = a1;
    // reduce qb
    float pb = qs[tid] * wv_b[tid] + qs[tid + 256] * wv_b[tid + 256];
    #pragma unroll
    for (int off = 32; off > 0; off >>= 1) pb += __shfl_down(pb, off, 64);
    __shared__ float red[4];
    if ((tid & 63) == 0) red[tid >> 6] = pb;
    __syncthreads();
    if (tid == 0) qb[b * NS + s] = (red[0] + red[1]) + (red[2] + red[3]);
}

// word attention fully fp32: logits[s,n] = qw[s,:]·key[:,n] + qb[s];
// softmax over s, mask, renorm -> attnw[b,s,n]
__global__ __launch_bounds__(256)
void word_attn(const float* __restrict__ key, const float* __restrict__ qw,
               const float* __restrict__ qb, const int* __restrict__ wid,
               float* __restrict__ attnw)
{
    __shared__ float qsh[NS][NC];   // 40 KB
    __shared__ float msk[NS];
    __shared__ float qbs[NS];
    const int b = blockIdx.y;
    const int tid = threadIdx.x;
    for (int idx = tid; idx < NS * NC; idx += 256)
        qsh[idx >> 9][idx & 511] = qw[(size_t)b * NS * NC + idx];
    if (tid < NS) {
        msk[tid] = (wid[b * NS + tid] != 0) ? 1.f : 0.f;
        qbs[tid] = qb[b * NS + tid];
    }
    __syncthreads();
    const int n = blockIdx.x * 256 + tid;
    const float* kb = key + (size_t)b * NC * NHW + n;
    float acc[NS];
    #pragma unroll
    for (int s = 0; s < NS; ++s) acc[s] = qbs[s];
    for (int c = 0; c < NC; ++c) {
        float vv = kb[(size_t)c * NHW];
        #pragma unroll
        for (int s = 0; s < NS; ++s) acc[s] += qsh[s][c] * vv;
    }
    float mx = acc[0];
    #pragma unroll
    for (int s = 1; s < NS; ++s) mx = fmaxf(mx, acc[s]);
    float sum = 0.f;
    #pragma unroll
    for (int s = 0; s < NS; ++s) { acc[s] = __expf(acc[s] - mx); sum += acc[s]; }
    const float inv = 1.f / sum;
    float msum = 0.f;
    #pragma unroll
    for (int s = 0; s < NS; ++s) { acc[s] *= inv * msk[s]; msum += acc[s]; }
    const float rr = 1.f / msum;
    #pragma unroll
    for (int s = 0; s < NS; ++s)
        attnw[((size_t)b * NS + s) * NHW + n] = acc[s] * rr;
}

// wembT[n][c] = sum_s attnw[s][n]*query[s][c] -> catT[b][n][512+c] bf16
__global__ __launch_bounds__(256)
void word_emb(const float* __restrict__ attnw, const float* __restrict__ query,
              u16* __restrict__ catT)
{
    __shared__ float qsh[NS][NC];
    const int b = blockIdx.y;
    const int tid = threadIdx.x;
    for (int idx = tid; idx < NS * NC; idx += 256)
        qsh[idx >> 9][idx & 511] = query[(size_t)b * NS * NC + idx];
    __syncthreads();
    const int n0 = blockIdx.x * 8;
    const int c = tid * 2;
    for (int nn = 0; nn < 8; ++nn) {
        const int n = n0 + nn;
        float a0 = 0.f, a1 = 0.f;
        #pragma unroll
        for (int s = 0; s < NS; ++s) {
            float aw = attnw[((size_t)b * NS + s) * NHW + n];
            a0 += aw * qsh[s][c];
            a1 += aw * qsh[s][c + 1];
        }
        unsigned int pk = (unsigned int)f2b(a0) | ((unsigned int)f2b(a1) << 16);
        *(unsigned int*)(catT + ((size_t)b * NHW + n) * 1024 + 512 + c) = pk;
    }
}

// in-place row softmax on bf16 scores (rows of length 2304)
__global__ __launch_bounds__(256)
void softmax_bf16(u16* __restrict__ S)
{
    u16* row = S + ((size_t)blockIdx.y * NHW + blockIdx.x) * NHW;
    const int tid = threadIdx.x;
    float v[9];
    float mx = -1e30f;
    #pragma unroll
    for (int i = 0; i < 9; ++i) { v[i] = b2f(row[tid + i * 256]); mx = fmaxf(mx, v[i]); }
    __shared__ float red[4];
    #pragma unroll
    for (int off = 32; off > 0; off >>= 1) mx = fmaxf(mx, __shfl_down(mx, off, 64));
    if ((tid & 63) == 0) red[tid >> 6] = mx;
    __syncthreads();
    mx = fmaxf(fmaxf(red[0], red[1]), fmaxf(red[2], red[3]));
    float sum = 0.f;
    #pragma unroll
    for (int i = 0; i < 9; ++i) { v[i] = __expf(v[i] - mx); sum += v[i]; }
    __shared__ float red2[4];
    #pragma unroll
    for (int off = 32; off > 0; off >>= 1) sum += __shfl_down(sum, off, 64);
    if ((tid & 63) == 0) red2[tid >> 6] = sum;
    __syncthreads();
    sum = (red2[0] + red2[1]) + (red2[2] + red2[3]);
    const float inv = 1.f / sum;
    #pragma unroll
    for (int i = 0; i < 9; ++i) row[tid + i * 256] = f2b(v[i] * inv);
}

extern "C" void kernel_launch(void* const* d_in, const int* in_sizes, int n_in,
                              void* d_out, int out_size, void* d_ws, size_t ws_size,
                              hipStream_t stream)
{
    const float* key   = (const float*)d_in[0];
    const float* query = (const float*)d_in[1];
    const int*   wid   = (const int*)d_in[2];
    const float* wv_w  = (const float*)d_in[3];
    const float* wv_b  = (const float*)d_in[4];
    const float* fk_w  = (const float*)d_in[5];
    const float* fk_b  = (const float*)d_in[6];
    const float* fq_w  = (const float*)d_in[7];
    const float* fq_b  = (const float*)d_in[8];
    const float* fv_w  = (const float*)d_in[9];
    const float* fv_b  = (const float*)d_in[10];
    const float* w1_w  = (const float*)d_in[11];
    const float* w1_b  = (const float*)d_in[12];
    const float* w2_w  = (const float*)d_in[13];
    const float* w2_b  = (const float*)d_in[14];
    float* out = (float*)d_out;

    char* p = (char*)d_ws;
    u16*   keyT  = (u16*)p;            p += (size_t)NB * NHW * NC * 2;       // 18.9 MB
    u16*   kT    = (u16*)p;            p += (size_t)NB * NHW * 256 * 2;      // 9.4 MB
    u16*   qT    = (u16*)p;            p += (size_t)NB * NHW * 256 * 2;      // 9.4 MB
    u16*   vbuf  = (u16*)p;            p += (size_t)NB * NC * NHW * 2;       // 18.9 MB
    u16*   catT  = (u16*)p;            p += (size_t)NB * NHW * 1024 * 2;     // 37.7 MB
    u16*   S     = (u16*)p;            p += (size_t)NB * NHW * NHW * 2;      // 84.9 MB
    float* attnw = (float*)p;          p += (size_t)NB * NS * NHW * 4;       // 1.5 MB
    float* qw    = (float*)p;          p += (size_t)NB * NS * NC * 4;        // 0.33 MB
    float* qb    = (float*)p;          p += (size_t)NB * NS * 4;
    u16*   fkb   = (u16*)p;            p += (size_t)256 * 512 * 2;
    u16*   fqb   = (u16*)p;            p += (size_t)256 * 512 * 2;
    u16*   fvb   = (u16*)p;            p += (size_t)512 * 512 * 2;
    u16*   wcombb= (u16*)p;            p += (size_t)512 * 1024 * 2;
    float* bcomb = (float*)p;          p += 512 * 4;

    dim3 blk(256);

    conv_weights<<<dim3(2048), blk, 0, stream>>>(fk_w, fq_w, fv_w, fkb, fqb, fvb);
    make_wcomb<<<dim3(512), blk, 0, stream>>>(w1_w, w1_b, w2_w, w2_b, wcombb, bcomb);
    transpose_key<<<dim3(36, 8, NB), blk, 0, stream>>>(key, keyT);

    // word attention, fully fp32 (reassociated through qw = query@wv)
    fold_query_wv<<<dim3(NS, NB), blk, 0, stream>>>(query, wv_w, wv_b, qw, qb);
    word_attn<<<dim3(9, NB), blk, 0, stream>>>(key, qw, qb, wid, attnw);
    word_emb<<<dim3(288, NB), blk, 0, stream>>>(attnw, query, catT);

    // kT (n,256): A=keyT, B=fk
    gemm_nt_bf16<<<dim3(2, 18, NB), blk, 0, stream>>>(
        keyT, (long)NHW * 512, 512, fkb, 0, 512,
        kT, (long)NHW * 256, 256, 512, fk_b, 2, 1.f, 0);
    // v (c,n): A=fv, B=keyT
    gemm_nt_bf16<<<dim3(18, 4, NB), blk, 0, stream>>>(
        fvb, 0, 512, keyT, (long)NHW * 512, 512,
        vbuf, (long)NC * NHW, NHW, 512, fv_b, 1, 1.f, 0);
    // qT (n,256): A=catT[:,512:], B=fq
    gemm_nt_bf16<<<dim3(2, 18, NB), blk, 0, stream>>>(
        catT + 512, (long)NHW * 1024, 1024, fqb, 0, 512,
        qT, (long)NHW * 256, 256, 512, fq_b, 2, 1.f, 0);
    // S (n,m): A=qT, B=kT, scale 1/16
    gemm_nt_bf16<<<dim3(18, 18, NB), blk, 0, stream>>>(
        qT, (long)NHW * 256, 256, kT, (long)NHW * 256, 256,
        S, (long)NHW * NHW, NHW, 256, nullptr, 0, 0.0625f, 0);
    softmax_bf16<<<dim3(NHW, NB), blk, 0, stream>>>(S);
    // ctxT (n,c) -> catT[:, :, 0:512]: A=P, B=v
    gemm_nt_bf16<<<dim3(4, 18, NB), blk, 0, stream>>>(
        S, (long)NHW * NHW, NHW, vbuf, (long)NC * NHW, NHW,
        catT, (long)NHW * 1024, 1024, NHW, nullptr, 0, 1.f, 0);
    // out (o,n) fp32: A=wcomb (512x1024), B=catT
    gemm_nt_bf16<<<dim3(18, 4, NB), blk, 0, stream>>>(
        wcombb, 0, 1024, catT, (long)NHW * 1024, 1024,
        out, (long)NC * NHW, NHW, 1024, bcomb, 1, 1.f, 1);
}

// Round 4
// 378.401 us; speedup vs baseline: 7.1145x; 1.1911x over previous
//
#include <hip/hip_runtime.h>

#define NHW 2304
#define NB  8
#define NS  20
#define NC  512

typedef unsigned short u16;
typedef short short8 __attribute__((ext_vector_type(8)));
typedef unsigned short u16x8 __attribute__((ext_vector_type(8)));
typedef float f32x4 __attribute__((ext_vector_type(4)));

__device__ __forceinline__ float b2f(u16 u) {
    unsigned int v = ((unsigned int)u) << 16;
    return __builtin_bit_cast(float, v);
}
__device__ __forceinline__ u16 f2b(float f) {
    unsigned int u = __builtin_bit_cast(unsigned int, f);
    u += 0x7fffu + ((u >> 16) & 1u);
    return (u16)(u >> 16);
}

__device__ __forceinline__ void load_lds16(const void* g, void* l) {
    __builtin_amdgcn_global_load_lds((const __attribute__((address_space(1))) void*)g,
                                     (__attribute__((address_space(3))) void*)l, 16, 0, 0);
}

// ---------------------------------------------------------------------------
// Uniform bf16 NT GEMM: C[b](MxN) = scale * A[b](MxK,lda) * B[b](NxK,ldb)^T (+bias)
// M,N multiples of 128; K multiple of 32. 256 thr, 4 waves 2x2, 128x128 tile.
// bias_mode: 0 none, 1 per-row, 2 per-col. out_f32: 1 fp32 else bf16.
// ---------------------------------------------------------------------------
__global__ __launch_bounds__(256)
void gemm_nt_bf16(const u16* __restrict__ A, long As, int lda,
                  const u16* __restrict__ B, long Bs, int ldb,
                  void* __restrict__ C, long Cs, int ldc,
                  int K, const float* __restrict__ bias, int bias_mode,
                  float scale, int out_f32)
{
    __shared__ __align__(16) u16 sA[128 * 32];
    __shared__ __align__(16) u16 sB[128 * 32];
    const int tid   = threadIdx.x;
    const int b     = blockIdx.z;
    const int nBase = blockIdx.x * 128;
    const int mBase = blockIdx.y * 128;
    const u16* Ab = A + (size_t)b * As + (size_t)mBase * lda;
    const u16* Bb = B + (size_t)b * Bs + (size_t)nBase * ldb;
    const int lane = tid & 63;
    const int wave = tid >> 6;
    const int wr = wave >> 1, wc = wave & 1;
    const int str = tid >> 2;
    const int stk = (tid & 3) * 8;
    f32x4 acc[4][4] = {};
    for (int k0 = 0; k0 < K; k0 += 32) {
        __syncthreads();
        load_lds16(&Ab[(size_t)str * lda + k0 + stk],        &sA[tid * 8]);
        load_lds16(&Ab[(size_t)(str + 64) * lda + k0 + stk], &sA[2048 + tid * 8]);
        load_lds16(&Bb[(size_t)str * ldb + k0 + stk],        &sB[tid * 8]);
        load_lds16(&Bb[(size_t)(str + 64) * ldb + k0 + stk], &sB[2048 + tid * 8]);
        __syncthreads();
        short8 af[4], bg[4];
        #pragma unroll
        for (int i = 0; i < 4; ++i)
            af[i] = *(const short8*)&sA[(wr * 64 + i * 16 + (lane & 15)) * 32 + (lane >> 4) * 8];
        #pragma unroll
        for (int j = 0; j < 4; ++j)
            bg[j] = *(const short8*)&sB[(wc * 64 + j * 16 + (lane & 15)) * 32 + (lane >> 4) * 8];
        #pragma unroll
        for (int i = 0; i < 4; ++i)
            #pragma unroll
            for (int j = 0; j < 4; ++j)
                acc[i][j] = __builtin_amdgcn_mfma_f32_16x16x32_bf16(af[i], bg[j], acc[i][j], 0, 0, 0);
    }
    const int r0 = mBase + wr * 64 + (lane >> 4) * 4;
    const int c0 = nBase + wc * 64 + (lane & 15);
    #pragma unroll
    for (int i = 0; i < 4; ++i) {
        #pragma unroll
        for (int r = 0; r < 4; ++r) {
            const int row = r0 + i * 16 + r;
            const float br = (bias_mode == 1) ? bias[row] : 0.f;
            #pragma unroll
            for (int j = 0; j < 4; ++j) {
                const int col = c0 + j * 16;
                float v = acc[i][j][r] * scale;
                v += (bias_mode == 2) ? bias[col] : br;
                if (out_f32)
                    ((float*)C)[(size_t)b * Cs + (size_t)row * ldc + col] = v;
                else
                    ((u16*)C)[(size_t)b * Cs + (size_t)row * ldc + col] = f2b(v);
            }
        }
    }
}

// key (B,512,2304) fp32 -> keyT (B,2304,512) bf16, 64x64 tiles via LDS
__global__ __launch_bounds__(256)
void transpose_key(const float* __restrict__ key, u16* __restrict__ keyT)
{
    __shared__ u16 t[64][72];
    const int b = blockIdx.z;
    const int nBase = blockIdx.x * 64;
    const int cBase = blockIdx.y * 64;
    const int tid = threadIdx.x;
    const float* kb = key + ((size_t)b * NC + cBase) * NHW + nBase;
    const int ln = tid & 63;
    const int lc = tid >> 6;
    #pragma unroll
    for (int r = 0; r < 16; ++r) {
        int c = lc + r * 4;
        t[c][ln] = f2b(kb[(size_t)c * NHW + ln]);
    }
    __syncthreads();
    u16* ob = keyT + ((size_t)b * NHW + nBase) * NC + cBase;
    #pragma unroll
    for (int r = 0; r < 2; ++r) {
        int slot = r * 256 + tid;
        int n = slot >> 3;
        int c0 = (slot & 7) * 8;
        u16x8 v;
        #pragma unroll
        for (int e = 0; e < 8; ++e) v[e] = t[c0 + e][n];
        *(u16x8*)&ob[(size_t)n * NC + c0] = v;
    }
}

__global__ __launch_bounds__(256)
void conv_weights(const float* __restrict__ fk, const float* __restrict__ fq,
                  const float* __restrict__ fv,
                  u16* __restrict__ fkb, u16* __restrict__ fqb, u16* __restrict__ fvb)
{
    int idx = blockIdx.x * 256 + threadIdx.x;   // 524288 total
    if (idx < 131072) fkb[idx] = f2b(fk[idx]);
    else if (idx < 262144) fqb[idx - 131072] = f2b(fq[idx - 131072]);
    else fvb[idx - 262144] = f2b(fv[idx - 262144]);
}

__global__ __launch_bounds__(256)
void make_wcomb(const float* __restrict__ w1, const float* __restrict__ w1b,
                const float* __restrict__ w2, const float* __restrict__ w2b,
                u16* __restrict__ wcb, float* __restrict__ bcomb)
{
    const int o = blockIdx.x;
    const int t = threadIdx.x;
    for (int c = t; c < 1024; c += 256)
        wcb[o * 1024 + c] = f2b(w1[o * 1024 + c] + (c < 512 ? w2[o * 512 + c] : 0.f));
    if (t == 0) bcomb[o] = w1b[o] + w2b[o];
}

// qw[b,s,c] = sum_o query[b,s,o] * wv_w[o,c];  qb[b,s] = sum_o query[b,s,o]*wv_b[o]
__global__ __launch_bounds__(256)
void fold_query_wv(const float* __restrict__ query, const float* __restrict__ wv_w,
                   const float* __restrict__ wv_b,
                   float* __restrict__ qw, float* __restrict__ qb)
{
    __shared__ float qs[NC];
    const int b = blockIdx.y, s = blockIdx.x;
    const int tid = threadIdx.x;
    qs[tid] = query[((size_t)b * NS + s) * NC + tid];
    qs[tid + 256] = query[((size_t)b * NS + s) * NC + tid + 256];
    __syncthreads();
    float a0 = 0.f, a1 = 0.f;
    for (int o = 0; o < NC; ++o) {
        float qv = qs[o];
        a0 += qv * wv_w[(size_t)o * NC + tid];
        a1 += qv * wv_w[(size_t)o * NC + tid + 256];
    }
    qw[((size_t)b * NS + s) * NC + tid] = a0;
    qw[((size_t)b * NS + s) * NC + tid + 256] = a1;
    float pb = qs[tid] * wv_b[tid] + qs[tid + 256] * wv_b[tid + 256];
    #pragma unroll
    for (int off = 32; off > 0; off >>= 1) pb += __shfl_down(pb, off, 64);
    __shared__ float red[4];
    if ((tid & 63) == 0) red[tid >> 6] = pb;
    __syncthreads();
    if (tid == 0) qb[b * NS + s] = (red[0] + red[1]) + (red[2] + red[3]);
}

// word attention fp32, latency-optimized: block covers 64 n, 4 waves split c.
// logits[s,n] = qw[s,:]·key[:,n] + qb[s]; masked softmax over s -> attnw
__global__ __launch_bounds__(256)
void word_attn(const float* __restrict__ key, const float* __restrict__ qw,
               const float* __restrict__ qb, const int* __restrict__ wid,
               float* __restrict__ attnw)
{
    __shared__ float qshT[NC][NS];     // [c][s], 40 KB; wave-uniform reads
    __shared__ float red[3][64][5];    // 3.8 KB cross-wave reduction scratch
    __shared__ float msk[NS], qbs[NS];
    const int b = blockIdx.y;
    const int tid = threadIdx.x;
    const float* qwb = qw + (size_t)b * NS * NC;
    for (int idx = tid; idx < NS * NC; idx += 256) {
        int c = idx / NS, s = idx - c * NS;
        qshT[c][s] = qwb[s * NC + c];
    }
    if (tid < NS) {
        msk[tid] = (wid[b * NS + tid] != 0) ? 1.f : 0.f;
        qbs[tid] = qb[b * NS + tid];
    }
    __syncthreads();
    const int wave = tid >> 6, lane = tid & 63;
    const int n = blockIdx.x * 64 + lane;
    const int cbase = wave * 128;
    const float* kp = key + (size_t)b * NC * NHW + n;
    float acc[NS];
    #pragma unroll
    for (int s = 0; s < NS; ++s) acc[s] = (wave == 0) ? qbs[s] : 0.f;
    #pragma unroll 8
    for (int ci = 0; ci < 128; ++ci) {
        const int c = cbase + ci;
        float kv = kp[(size_t)c * NHW];
        #pragma unroll
        for (int s = 0; s < NS; ++s) acc[s] += qshT[c][s] * kv;
    }
    #pragma unroll
    for (int r = 0; r < 4; ++r) {
        if (wave > 0) {
            #pragma unroll
            for (int k = 0; k < 5; ++k) red[wave - 1][lane][k] = acc[r * 5 + k];
        }
        __syncthreads();
        if (wave == 0) {
            #pragma unroll
            for (int k = 0; k < 5; ++k)
                acc[r * 5 + k] += red[0][lane][k] + red[1][lane][k] + red[2][lane][k];
        }
        __syncthreads();
    }
    if (wave == 0) {
        float mx = acc[0];
        #pragma unroll
        for (int s = 1; s < NS; ++s) mx = fmaxf(mx, acc[s]);
        float msum = 0.f;
        #pragma unroll
        for (int s = 0; s < NS; ++s) {
            acc[s] = __expf(acc[s] - mx) * msk[s];
            msum += acc[s];
        }
        const float rr = 1.f / msum;
        #pragma unroll
        for (int s = 0; s < NS; ++s)
            attnw[((size_t)b * NS + s) * NHW + n] = acc[s] * rr;
    }
}

// wembT[n][c] = sum_s attnw[s][n]*query[s][c] -> catT[b][n][512+c] bf16
__global__ __launch_bounds__(256)
void word_emb(const float* __restrict__ attnw, const float* __restrict__ query,
              u16* __restrict__ catT)
{
    __shared__ float qsh[NS][NC];
    const int b = blockIdx.y;
    const int tid = threadIdx.x;
    for (int idx = tid; idx < NS * NC; idx += 256)
        qsh[idx >> 9][idx & 511] = query[(size_t)b * NS * NC + idx];
    __syncthreads();
    const int n0 = blockIdx.x * 8;
    const int c = tid * 2;
    for (int nn = 0; nn < 8; ++nn) {
        const int n = n0 + nn;
        float a0 = 0.f, a1 = 0.f;
        #pragma unroll
        for (int s = 0; s < NS; ++s) {
            float aw = attnw[((size_t)b * NS + s) * NHW + n];
            a0 += aw * qsh[s][c];
            a1 += aw * qsh[s][c + 1];
        }
        unsigned int pk = (unsigned int)f2b(a0) | ((unsigned int)f2b(a1) << 16);
        *(unsigned int*)(catT + ((size_t)b * NHW + n) * 1024 + 512 + c) = pk;
    }
}

// in-place row softmax on bf16 scores (rows of length 2304)
__global__ __launch_bounds__(256)
void softmax_bf16(u16* __restrict__ S)
{
    u16* row = S + ((size_t)blockIdx.y * NHW + blockIdx.x) * NHW;
    const int tid = threadIdx.x;
    float v[9];
    float mx = -1e30f;
    #pragma unroll
    for (int i = 0; i < 9; ++i) { v[i] = b2f(row[tid + i * 256]); mx = fmaxf(mx, v[i]); }
    __shared__ float red[4];
    #pragma unroll
    for (int off = 32; off > 0; off >>= 1) mx = fmaxf(mx, __shfl_down(mx, off, 64));
    if ((tid & 63) == 0) red[tid >> 6] = mx;
    __syncthreads();
    mx = fmaxf(fmaxf(red[0], red[1]), fmaxf(red[2], red[3]));
    float sum = 0.f;
    #pragma unroll
    for (int i = 0; i < 9; ++i) { v[i] = __expf(v[i] - mx); sum += v[i]; }
    __shared__ float red2[4];
    #pragma unroll
    for (int off = 32; off > 0; off >>= 1) sum += __shfl_down(sum, off, 64);
    if ((tid & 63) == 0) red2[tid >> 6] = sum;
    __syncthreads();
    sum = (red2[0] + red2[1]) + (red2[2] + red2[3]);
    const float inv = 1.f / sum;
    #pragma unroll
    for (int i = 0; i < 9; ++i) row[tid + i * 256] = f2b(v[i] * inv);
}

extern "C" void kernel_launch(void* const* d_in, const int* in_sizes, int n_in,
                              void* d_out, int out_size, void* d_ws, size_t ws_size,
                              hipStream_t stream)
{
    const float* key   = (const float*)d_in[0];
    const float* query = (const float*)d_in[1];
    const int*   wid   = (const int*)d_in[2];
    const float* wv_w  = (const float*)d_in[3];
    const float* wv_b  = (const float*)d_in[4];
    const float* fk_w  = (const float*)d_in[5];
    const float* fk_b  = (const float*)d_in[6];
    const float* fq_w  = (const float*)d_in[7];
    const float* fq_b  = (const float*)d_in[8];
    const float* fv_w  = (const float*)d_in[9];
    const float* fv_b  = (const float*)d_in[10];
    const float* w1_w  = (const float*)d_in[11];
    const float* w1_b  = (const float*)d_in[12];
    const float* w2_w  = (const float*)d_in[13];
    const float* w2_b  = (const float*)d_in[14];
    float* out = (float*)d_out;

    char* p = (char*)d_ws;
    u16*   keyT  = (u16*)p;            p += (size_t)NB * NHW * NC * 2;       // 18.9 MB
    u16*   kT    = (u16*)p;            p += (size_t)NB * NHW * 256 * 2;      // 9.4 MB
    u16*   qT    = (u16*)p;            p += (size_t)NB * NHW * 256 * 2;      // 9.4 MB
    u16*   vbuf  = (u16*)p;            p += (size_t)NB * NC * NHW * 2;       // 18.9 MB
    u16*   catT  = (u16*)p;            p += (size_t)NB * NHW * 1024 * 2;     // 37.7 MB
    u16*   S     = (u16*)p;            p += (size_t)NB * NHW * NHW * 2;      // 84.9 MB
    float* attnw = (float*)p;          p += (size_t)NB * NS * NHW * 4;       // 1.5 MB
    float* qw    = (float*)p;          p += (size_t)NB * NS * NC * 4;        // 0.33 MB
    float* qb    = (float*)p;          p += (size_t)NB * NS * 4;
    u16*   fkb   = (u16*)p;            p += (size_t)256 * 512 * 2;
    u16*   fqb   = (u16*)p;            p += (size_t)256 * 512 * 2;
    u16*   fvb   = (u16*)p;            p += (size_t)512 * 512 * 2;
    u16*   wcombb= (u16*)p;            p += (size_t)512 * 1024 * 2;
    float* bcomb = (float*)p;          p += 512 * 4;

    dim3 blk(256);

    conv_weights<<<dim3(2048), blk, 0, stream>>>(fk_w, fq_w, fv_w, fkb, fqb, fvb);
    make_wcomb<<<dim3(512), blk, 0, stream>>>(w1_w, w1_b, w2_w, w2_b, wcombb, bcomb);
    transpose_key<<<dim3(36, 8, NB), blk, 0, stream>>>(key, keyT);

    // word attention, fully fp32 (reassociated through qw = query@wv)
    fold_query_wv<<<dim3(NS, NB), blk, 0, stream>>>(query, wv_w, wv_b, qw, qb);
    word_attn<<<dim3(36, NB), blk, 0, stream>>>(key, qw, qb, wid, attnw);
    word_emb<<<dim3(288, NB), blk, 0, stream>>>(attnw, query, catT);

    // kT (n,256): A=keyT, B=fk
    gemm_nt_bf16<<<dim3(2, 18, NB), blk, 0, stream>>>(
        keyT, (long)NHW * 512, 512, fkb, 0, 512,
        kT, (long)NHW * 256, 256, 512, fk_b, 2, 1.f, 0);
    // v (c,n): A=fv, B=keyT
    gemm_nt_bf16<<<dim3(18, 4, NB), blk, 0, stream>>>(
        fvb, 0, 512, keyT, (long)NHW * 512, 512,
        vbuf, (long)NC * NHW, NHW, 512, fv_b, 1, 1.f, 0);
    // qT (n,256): A=catT[:,512:], B=fq
    gemm_nt_bf16<<<dim3(2, 18, NB), blk, 0, stream>>>(
        catT + 512, (long)NHW * 1024, 1024, fqb, 0, 512,
        qT, (long)NHW * 256, 256, 512, fq_b, 2, 1.f, 0);
    // S (n,m): A=qT, B=kT, scale 1/16
    gemm_nt_bf16<<<dim3(18, 18, NB), blk, 0, stream>>>(
        qT, (long)NHW * 256, 256, kT, (long)NHW * 256, 256,
        S, (long)NHW * NHW, NHW, 256, nullptr, 0, 0.0625f, 0);
    softmax_bf16<<<dim3(NHW, NB), blk, 0, stream>>>(S);
    // ctxT (n,c) -> catT[:, :, 0:512]: A=P, B=v
    gemm_nt_bf16<<<dim3(4, 18, NB), blk, 0, stream>>>(
        S, (long)NHW * NHW, NHW, vbuf, (long)NC * NHW, NHW,
        catT, (long)NHW * 1024, 1024, NHW, nullptr, 0, 1.f, 0);
    // out (o,n) fp32: A=wcomb (512x1024), B=catT
    gemm_nt_bf16<<<dim3(18, 4, NB), blk, 0, stream>>>(
        wcombb, 0, 1024, catT, (long)NHW * 1024, 1024,
        out, (long)NC * NHW, NHW, 1024, bcomb, 1, 1.f, 1);
}